// Round 4
// baseline (111.943 us; speedup 1.0000x reference)
//
#include <hip/hip_runtime.h>
#include <math.h>

#define TT   4096          // tokens (B*S)
#define HH   4096          // hidden
#define EE   8             // experts
#define KTOP 2
#define CAP  1280          // capacity = int(T*K/E*1.25)
#define TEC  ((size_t)TT * EE * CAP)   // 41,943,040

#define GATE_BLOCKS 256
#define ZERO_BLOCKS 4096
#define ASSIGN_BLOCKS 64   // 256 chunks of 32 items; 4 chunks per block

typedef __attribute__((ext_vector_type(4))) float f32x4;

// ---------------- ws layout ----------------
// ws_part: float[GATE_BLOCKS*9]  per-block partials ([0..7]=prob sums, [8]=z sum)
// ws_e:    int[T*K]
// ws_w:    float[T*K]

// Fused: blocks [0,256) do the gate GEMV for 16 tokens each;
//        blocks [256,4352) zero d_out[0, 2*TEC).
__global__ __launch_bounds__(256) void fused_kernel(
    const float* __restrict__ x, const float* __restrict__ W,
    float* __restrict__ out, float* __restrict__ ws_part,
    int* __restrict__ ws_e, float* __restrict__ ws_w)
{
    int tid = threadIdx.x;

    if (blockIdx.x >= GATE_BLOCKS) {
        // ---- zero path: contiguous 5120-float4 chunk per block ----
        // PLAIN stores this round (round-3 used nontemporal; single-variable A/B)
        size_t zb = blockIdx.x - GATE_BLOCKS;
        f32x4* p = (f32x4*)out;
        const size_t per = (2 * TEC / 4) / ZERO_BLOCKS;   // 5120
        size_t base = zb * per;
        f32x4 z = {0.f, 0.f, 0.f, 0.f};
#pragma unroll 4
        for (size_t i = tid; i < per; i += 256)
            p[base + i] = z;
        return;
    }

    // ---- gate path ----
    __shared__ float bacc[9];
    if (tid < 9) bacc[tid] = 0.f;
    __syncthreads();

    int wave = tid >> 6;
    int lane = tid & 63;
    int t0 = (blockIdx.x * 4 + wave) * 4;   // 4 tokens per wave

    const float4* __restrict__ W4 = (const float4*)W;   // [8][1024]
    const float4* __restrict__ X4 = (const float4*)x;   // [T][1024]

    float acc[4][8];
#pragma unroll
    for (int tt = 0; tt < 4; ++tt)
#pragma unroll
        for (int e = 0; e < 8; ++e) acc[tt][e] = 0.f;

    for (int jj = 0; jj < 16; ++jj) {
        int ci = jj * 64 + lane;            // float4 column in [0,1024)
        float4 wv[8];
#pragma unroll
        for (int e = 0; e < 8; ++e) wv[e] = W4[e * 1024 + ci];
#pragma unroll
        for (int tt = 0; tt < 4; ++tt) {
            float4 xv = X4[(size_t)(t0 + tt) * 1024 + ci];
#pragma unroll
            for (int e = 0; e < 8; ++e) {
                acc[tt][e] = fmaf(xv.x, wv[e].x, acc[tt][e]);
                acc[tt][e] = fmaf(xv.y, wv[e].y, acc[tt][e]);
                acc[tt][e] = fmaf(xv.z, wv[e].z, acc[tt][e]);
                acc[tt][e] = fmaf(xv.w, wv[e].w, acc[tt][e]);
            }
        }
    }

    // 64-lane butterfly reduce
#pragma unroll
    for (int tt = 0; tt < 4; ++tt)
#pragma unroll
        for (int e = 0; e < 8; ++e) {
#pragma unroll
            for (int s = 32; s >= 1; s >>= 1)
                acc[tt][e] += __shfl_xor(acc[tt][e], s, 64);
        }

    if (lane == 0) {
        for (int tt = 0; tt < 4; ++tt) {
            int t = t0 + tt;
            float l[8];
#pragma unroll
            for (int e = 0; e < 8; ++e) l[e] = acc[tt][e];

            // full-softmax stats for aux losses
            float m = l[0];
#pragma unroll
            for (int e = 1; e < 8; ++e) m = fmaxf(m, l[e]);
            float p[8], s = 0.f;
#pragma unroll
            for (int e = 0; e < 8; ++e) { p[e] = expf(l[e] - m); s += p[e]; }
            float inv = 1.f / s;
#pragma unroll
            for (int e = 0; e < 8; ++e) atomicAdd(&bacc[e], p[e] * inv);
            atomicAdd(&bacc[8], m + logf(s));   // logsumexp

            // top-2 (ties -> lowest index)
            int i0 = 0;
#pragma unroll
            for (int e = 1; e < 8; ++e) if (l[e] > l[i0]) i0 = e;
            int i1 = (i0 == 0) ? 1 : 0;
#pragma unroll
            for (int e = 0; e < 8; ++e) if (e != i0 && l[e] > l[i1]) i1 = e;

            float w0 = 1.f / (1.f + expf(l[i1] - l[i0]));
            float w1 = 1.f - w0;

            float* out_topi = out + 2 * TEC;
            out_topi[t * 2 + 0] = (float)i0;
            out_topi[t * 2 + 1] = (float)i1;
            ws_e[t * 2 + 0] = i0;
            ws_e[t * 2 + 1] = i1;
            ws_w[t * 2 + 0] = w0;
            ws_w[t * 2 + 1] = w1;
        }
    }
    __syncthreads();
    if (tid < 9) ws_part[blockIdx.x * 9 + tid] = bacc[tid];
}

// ASSIGN_BLOCKS blocks x 256 threads. Every block redundantly computes the
// identical per-chunk exclusive prefix counts (cheap: 32KB L2-resident read),
// then scatters only its own 4 chunks -> scatter spreads over 64 CUs.
// Block 0 also reduces loss partials and writes the 2 scalars.
__global__ __launch_bounds__(256) void assign_kernel(
    const int* __restrict__ ws_e, const float* __restrict__ ws_w,
    const float* __restrict__ ws_part, float* __restrict__ out)
{
    __shared__ int   scnt[256][8];
    __shared__ int   ssum[8][8];     // [segment][expert]
    __shared__ int   stot[8];
    __shared__ float lacc[9];

    int tid = threadIdx.x;
    if (tid < 9) lacc[tid] = 0.f;
    __syncthreads();

    if (blockIdx.x == 0) {
        // reduce gate partials (one gate block per thread)
#pragma unroll
        for (int j = 0; j < 9; ++j)
            atomicAdd(&lacc[j], ws_part[tid * 9 + j]);
    }

    // per-thread expert counts over this thread's 32-item chunk
    const int PER = (TT * KTOP) / 256;   // 32
    int i0 = tid * PER;
    int cnt[8];
#pragma unroll
    for (int e = 0; e < 8; ++e) cnt[e] = 0;
    for (int j = 0; j < PER; ++j) cnt[ws_e[i0 + j]]++;
#pragma unroll
    for (int e = 0; e < 8; ++e) scnt[tid][e] = cnt[e];
    __syncthreads();

    // two-level exclusive scan over 256 chunks, per expert
    if (tid < 64) {                       // 8 segments x 8 experts
        int e = tid & 7, seg = tid >> 3;
        int run = 0;
        for (int j = seg * 32; j < seg * 32 + 32; ++j) {
            int v = scnt[j][e];
            scnt[j][e] = run;
            run += v;
        }
        ssum[seg][e] = run;
    }
    __syncthreads();
    if (tid < 8) {
        int run = 0;
        for (int s = 0; s < 8; ++s) {
            int v = ssum[s][tid];
            ssum[s][tid] = run;
            run += v;
        }
        stot[tid] = run;
    }
    __syncthreads();

    // scatter: block b owns chunks [4b, 4b+4)
    if ((tid >> 2) == blockIdx.x) {
        int seg = tid >> 5;
        int base[8];
#pragma unroll
        for (int e = 0; e < 8; ++e) base[e] = scnt[tid][e] + ssum[seg][e];

        for (int j = 0; j < PER; ++j) {
            int i = i0 + j;
            int e = ws_e[i];
            int pos = base[e]++;
            if (pos < CAP) {
                int tok = i >> 1;
                size_t idx = (size_t)tok * (EE * CAP) + (size_t)e * CAP + pos;
                out[idx] = 1.0f;              // dispatch_mask
                out[TEC + idx] = ws_w[i];     // combine_weights
            }
        }
    }

    if (blockIdx.x == 0 && tid == 0) {
        int tot_valid = 0;
        int ve[8];
#pragma unroll
        for (int e = 0; e < 8; ++e) { ve[e] = min(stot[e], CAP); tot_valid += ve[e]; }
        float lbl = 0.f;
#pragma unroll
        for (int e = 0; e < 8; ++e)
            lbl += (lacc[e] / (float)TT) * ((float)ve[e] / (float)tot_valid);
        lbl *= 0.01f * (float)EE;
        float zl = 0.001f * lacc[8] / (float)TT;
        out[2 * TEC + TT * KTOP + 0] = lbl;
        out[2 * TEC + TT * KTOP + 1] = zl;
    }
}

extern "C" void kernel_launch(void* const* d_in, const int* in_sizes, int n_in,
                              void* d_out, int out_size, void* d_ws, size_t ws_size,
                              hipStream_t stream) {
    const float* x = (const float*)d_in[0];   // [4,1024,4096] -> [T,H]
    const float* W = (const float*)d_in[1];   // [E,H]
    float* out = (float*)d_out;

    float* ws_part = (float*)d_ws;                                     // 256*9 floats
    int*   ws_e    = (int*)((char*)d_ws + GATE_BLOCKS * 9 * 4);        // T*K ints
    float* ws_w    = (float*)((char*)d_ws + GATE_BLOCKS * 9 * 4 + (size_t)TT * KTOP * 4);

    fused_kernel<<<GATE_BLOCKS + ZERO_BLOCKS, 256, 0, stream>>>(
        x, W, out, ws_part, ws_e, ws_w);

    assign_kernel<<<ASSIGN_BLOCKS, 256, 0, stream>>>(ws_e, ws_w, ws_part, out);
}

// Round 5
// 92.774 us; speedup vs baseline: 1.2066x; 1.2066x over previous
//
#include <hip/hip_runtime.h>
#include <math.h>

#define TT   4096          // tokens (B*S)
#define HH   4096          // hidden
#define EE   8             // experts
#define KTOP 2
#define CAP  1280          // capacity = int(T*K/E*1.25)
#define TEC  ((size_t)TT * EE * CAP)   // 41,943,040

#define NBLK 4096          // one block per token; also zeroes 2*TEC/NBLK floats
#define ASSIGN_BLOCKS 64   // 256 chunks of 32 items; 4 chunks per block

typedef __attribute__((ext_vector_type(4))) float f32x4;

// ---------------- ws layout ----------------
// ws_part: float[NBLK*9]  per-token partials ([0..7]=softmax probs, [8]=logsumexp)
// ws_e:    int[T*K]
// ws_w:    float[T*K]

// Each block b: (1) computes token b's 8 gate logits (4 waves split H 4-ways,
// 64-lane butterfly + LDS combine), (2) zeroes its contiguous 5120-float4
// chunk of out[0, 2*TEC) with nontemporal stores (NT proven +17us in r3/r4 A/B).
__global__ __launch_bounds__(256) void fused_kernel(
    const float* __restrict__ x, const float* __restrict__ W,
    float* __restrict__ out, float* __restrict__ ws_part,
    int* __restrict__ ws_e, float* __restrict__ ws_w)
{
    __shared__ float wpart[4][8];

    int tid  = threadIdx.x;
    int wave = tid >> 6;
    int lane = tid & 63;
    int t    = blockIdx.x;

    const float4* __restrict__ X4 = (const float4*)x + (size_t)t * 1024;
    const float4* __restrict__ W4 = (const float4*)W;   // [8][1024]

    // ---- gate: this wave covers float4 cols [wave*256, wave*256+256) ----
    float acc[8];
#pragma unroll
    for (int e = 0; e < 8; ++e) acc[e] = 0.f;

#pragma unroll
    for (int j = 0; j < 4; ++j) {
        int ci = wave * 256 + j * 64 + lane;
        float4 xv = X4[ci];
#pragma unroll
        for (int e = 0; e < 8; ++e) {
            float4 wv = W4[e * 1024 + ci];
            acc[e] = fmaf(xv.x, wv.x, acc[e]);
            acc[e] = fmaf(xv.y, wv.y, acc[e]);
            acc[e] = fmaf(xv.z, wv.z, acc[e]);
            acc[e] = fmaf(xv.w, wv.w, acc[e]);
        }
    }

    // 64-lane butterfly reduce per expert
#pragma unroll
    for (int e = 0; e < 8; ++e) {
#pragma unroll
        for (int s = 32; s >= 1; s >>= 1)
            acc[e] += __shfl_xor(acc[e], s, 64);
    }
    if (lane == 0) {
#pragma unroll
        for (int e = 0; e < 8; ++e) wpart[wave][e] = acc[e];
    }

    // ---- zero this block's chunk (NT stores, issued while sync drains) ----
    {
        f32x4* p = (f32x4*)out + (size_t)t * ((2 * TEC / 4) / NBLK);  // 5120/blk
        f32x4 z = {0.f, 0.f, 0.f, 0.f};
#pragma unroll 4
        for (int i = tid; i < (int)((2 * TEC / 4) / NBLK); i += 256)
            __builtin_nontemporal_store(z, &p[i]);
    }

    __syncthreads();

    if (tid == 0) {
        float l[8];
#pragma unroll
        for (int e = 0; e < 8; ++e)
            l[e] = wpart[0][e] + wpart[1][e] + wpart[2][e] + wpart[3][e];

        // full-softmax stats for aux losses
        float m = l[0];
#pragma unroll
        for (int e = 1; e < 8; ++e) m = fmaxf(m, l[e]);
        float p[8], s = 0.f;
#pragma unroll
        for (int e = 0; e < 8; ++e) { p[e] = expf(l[e] - m); s += p[e]; }
        float inv = 1.f / s;
#pragma unroll
        for (int e = 0; e < 8; ++e) ws_part[t * 9 + e] = p[e] * inv;
        ws_part[t * 9 + 8] = m + logf(s);     // logsumexp

        // top-2 (ties -> lowest index)
        int i0 = 0;
#pragma unroll
        for (int e = 1; e < 8; ++e) if (l[e] > l[i0]) i0 = e;
        int i1 = (i0 == 0) ? 1 : 0;
#pragma unroll
        for (int e = 0; e < 8; ++e) if (e != i0 && l[e] > l[i1]) i1 = e;

        float w0 = 1.f / (1.f + expf(l[i1] - l[i0]));
        float w1 = 1.f - w0;

        float* out_topi = out + 2 * TEC;
        out_topi[t * 2 + 0] = (float)i0;
        out_topi[t * 2 + 1] = (float)i1;
        ws_e[t * 2 + 0] = i0;
        ws_e[t * 2 + 1] = i1;
        ws_w[t * 2 + 0] = w0;
        ws_w[t * 2 + 1] = w1;
    }
}

// ASSIGN_BLOCKS blocks x 256 threads. Every block redundantly computes the
// identical per-chunk exclusive prefix counts (32KB L2-resident read), then
// scatters only its own 4 chunks -> scatter spreads over 64 CUs.
// Block 0 also reduces loss partials and writes the 2 scalars.
__global__ __launch_bounds__(256) void assign_kernel(
    const int* __restrict__ ws_e, const float* __restrict__ ws_w,
    const float* __restrict__ ws_part, float* __restrict__ out)
{
    __shared__ int   scnt[256][8];
    __shared__ int   ssum[8][8];     // [segment][expert]
    __shared__ int   stot[8];
    __shared__ float lacc[9];

    int tid = threadIdx.x;
    if (tid < 9) lacc[tid] = 0.f;
    __syncthreads();

    if (blockIdx.x == 0) {
        // reduce 4096 token partials: 16 per thread, registers then LDS atomics
        float r[9];
#pragma unroll
        for (int j = 0; j < 9; ++j) r[j] = 0.f;
        for (int k = 0; k < NBLK / 256; ++k) {
            const float* q = ws_part + (size_t)(tid * (NBLK / 256) + k) * 9;
#pragma unroll
            for (int j = 0; j < 9; ++j) r[j] += q[j];
        }
#pragma unroll
        for (int j = 0; j < 9; ++j) atomicAdd(&lacc[j], r[j]);
    }

    // per-thread expert counts over this thread's 32-item chunk
    const int PER = (TT * KTOP) / 256;   // 32
    int i0 = tid * PER;
    int cnt[8];
#pragma unroll
    for (int e = 0; e < 8; ++e) cnt[e] = 0;
    for (int j = 0; j < PER; ++j) cnt[ws_e[i0 + j]]++;
#pragma unroll
    for (int e = 0; e < 8; ++e) scnt[tid][e] = cnt[e];
    __syncthreads();

    // two-level exclusive scan over 256 chunks, per expert
    if (tid < 64) {                       // 8 segments x 8 experts
        int e = tid & 7, seg = tid >> 3;
        int run = 0;
        for (int j = seg * 32; j < seg * 32 + 32; ++j) {
            int v = scnt[j][e];
            scnt[j][e] = run;
            run += v;
        }
        ssum[seg][e] = run;
    }
    __syncthreads();
    if (tid < 8) {
        int run = 0;
        for (int s = 0; s < 8; ++s) {
            int v = ssum[s][tid];
            ssum[s][tid] = run;
            run += v;
        }
        stot[tid] = run;
    }
    __syncthreads();

    // scatter: block b owns chunks [4b, 4b+4)
    if ((tid >> 2) == blockIdx.x) {
        int seg = tid >> 5;
        int base[8];
#pragma unroll
        for (int e = 0; e < 8; ++e) base[e] = scnt[tid][e] + ssum[seg][e];

        for (int j = 0; j < PER; ++j) {
            int i = i0 + j;
            int e = ws_e[i];
            int pos = base[e]++;
            if (pos < CAP) {
                int tok = i >> 1;
                size_t idx = (size_t)tok * (EE * CAP) + (size_t)e * CAP + pos;
                out[idx] = 1.0f;              // dispatch_mask
                out[TEC + idx] = ws_w[i];     // combine_weights
            }
        }
    }

    if (blockIdx.x == 0 && tid == 0) {
        int tot_valid = 0;
        int ve[8];
#pragma unroll
        for (int e = 0; e < 8; ++e) { ve[e] = min(stot[e], CAP); tot_valid += ve[e]; }
        float lbl = 0.f;
#pragma unroll
        for (int e = 0; e < 8; ++e)
            lbl += (lacc[e] / (float)TT) * ((float)ve[e] / (float)tot_valid);
        lbl *= 0.01f * (float)EE;
        float zl = 0.001f * lacc[8] / (float)TT;
        out[2 * TEC + TT * KTOP + 0] = lbl;
        out[2 * TEC + TT * KTOP + 1] = zl;
    }
}

extern "C" void kernel_launch(void* const* d_in, const int* in_sizes, int n_in,
                              void* d_out, int out_size, void* d_ws, size_t ws_size,
                              hipStream_t stream) {
    const float* x = (const float*)d_in[0];   // [4,1024,4096] -> [T,H]
    const float* W = (const float*)d_in[1];   // [E,H]
    float* out = (float*)d_out;

    float* ws_part = (float*)d_ws;                                   // NBLK*9 floats
    int*   ws_e    = (int*)((char*)d_ws + (size_t)NBLK * 9 * 4);     // T*K ints
    float* ws_w    = (float*)((char*)d_ws + (size_t)NBLK * 9 * 4 + (size_t)TT * KTOP * 4);

    fused_kernel<<<NBLK, 256, 0, stream>>>(x, W, out, ws_part, ws_e, ws_w);

    assign_kernel<<<ASSIGN_BLOCKS, 256, 0, stream>>>(ws_e, ws_w, ws_part, out);
}